// Round 12
// baseline (415.789 us; speedup 1.0000x reference)
//
#include <hip/hip_runtime.h>
#include <cfloat>
#include <cstdint>

#define BATCH 16
#define PRIORS 3000
#define NCLS 201
#define NLBL 200           // NCLS - 1
#define TOPN 100
#define SCORE_THR 0.02f
#define NMS_THR 0.45f

// Fused single-kernel design (R12): grid = 752 filter blocks + 16 nms
// blocks, 1024 threads each. Filter blocks signal per-block done-flags
// (device-scope release); nms blocks decode concurrently, then acquire-spin.
// R11 lessons: float4 filter and matrix-resolve were neutral; the stable
// ~90 us non-nms remainder is filter + 3 launch overheads -> fuse.
#define FPPB 64                              // priors per filter block (16 waves x 4)
#define FBLK ((PRIORS + FPPB - 1) / FPPB)    // 47 filter blocks/image
#define SEGW 64                              // slots per wave-segment
#define SEGS (FBLK * 16)                     // 752 segments/image
#define SLOTS (SEGS * SEGW)                  // 48128 slots/image
#define HOTW 8                               // hot slots per segment
#define OVF_CAP 1024
#define T0 0.08f           // hot threshold: ~315 hot/image (in [105,512] w/ margin)

#define NMS_T 1024
#define NBINS 1024         // strata over (key>>48)-SB_BASE (fallback only)
#define HCAP 512
#define SB_BASE 0x3CA3     // floatbits(0.02) >> 16
#define DONE_MAGIC 0x13579BDF   // != 0xAAAAAAAA poison, != 0 memset

__device__ __forceinline__ int key_stratum(uint64_t k) {
    int s = (int)(k >> 48) - SB_BASE;
    return s < 0 ? 0 : (s > NBINS - 1 ? NBINS - 1 : s);
}

// ---------------------------------------------------------------------------
// Wave-0 register bitonic sort of 512 u64 keys (8/lane), descending.
// ---------------------------------------------------------------------------
__device__ __forceinline__ void sort512_desc(const uint64_t* skey,
                                             uint64_t K[8], int lane)
{
#pragma unroll
    for (int r = 0; r < 8; ++r) K[r] = skey[r * 64 + lane];
#pragma unroll
    for (int k2 = 2; k2 <= 512; k2 <<= 1) {
#pragma unroll
        for (int j2 = k2 >> 1; j2 >= 64; j2 >>= 1) {     // register stages
            int j2r = j2 >> 6;
#pragma unroll
            for (int r = 0; r < 8; ++r) {
                if ((r & j2r) == 0) {
                    int rp = r | j2r;
                    bool up = ((((r << 6) + lane) & k2) == 0);
                    uint64_t a = K[r], bb = K[rp];
                    uint64_t mxk = a > bb ? a : bb;
                    uint64_t mnk = a > bb ? bb : a;
                    K[r]  = up ? mxk : mnk;
                    K[rp] = up ? mnk : mxk;
                }
            }
        }
#pragma unroll
        for (int j2 = ((k2 >> 1) < 32 ? (k2 >> 1) : 32); j2 >= 1; j2 >>= 1) {
#pragma unroll
            for (int r = 0; r < 8; ++r) {                // shuffle stages
                uint64_t o = __shfl_xor((unsigned long long)K[r], j2, 64);
                bool up = ((((r << 6) + lane) & k2) == 0);
                bool lower = ((lane & j2) == 0);
                K[r] = (up == lower) ? (K[r] > o ? K[r] : o)
                                     : (K[r] < o ? K[r] : o);
            }
        }
    }
}

// ---------------------------------------------------------------------------
// Wave-0 scan over sorted K[8] (desc): phase A parallel IoU vs accepted
// list; suppression-mask build; bit-dance greedy resolve. Accepted lane
// force-removed via self-bit (matches .at[i].set(-1)). Box/area/IoU
// expressions bit-identical to the reference's bo/areas.
// ---------------------------------------------------------------------------
__device__ __forceinline__ int scan_matrix_w0(
    const uint64_t K[8], int b, const float4* __restrict__ dbox, float ofb,
    float4* abox, float* aarea, int na, float* __restrict__ out, int lane)
{
#pragma unroll
    for (int r = 0; r < 8; ++r) {
        if (na >= TOPN) break;
        uint64_t myk = K[r];
        bool valid = (myk != 0ull);
        uint32_t oid = 0xFFFFFFFFu - (uint32_t)myk;
        int p = valid ? (int)(oid / NLBL) : 0;
        int c = valid ? ((int)(oid - (uint32_t)p * NLBL) + 1) : 1;
        float4 db = dbox[p];
        float lof = (float)c * ofb;
        float qx1 = db.x + lof, qy1 = db.y + lof;
        float qx2 = db.z + lof, qy2 = db.w + lof;
        float aq = (qx2 - qx1) * (qy2 - qy1);
        bool dead = false;
        for (int l = 0; l < na; ++l) {
            float4 a = abox[l];
            float ix1 = fmaxf(qx1, a.x), iy1 = fmaxf(qy1, a.y);
            float ix2 = fminf(qx2, a.z), iy2 = fminf(qy2, a.w);
            float inter = fmaxf(ix2 - ix1, 0.0f) * fmaxf(iy2 - iy1, 0.0f);
            float iou = inter / (aq + aarea[l] - inter);  // NaN>thr==false
            if (iou > NMS_THR) dead = true;
        }
        bool aliveB = valid && !dead;
        uint64_t alive = __ballot(aliveB);
        if (alive == 0ull) continue;
        uint64_t M = 0ull;
#pragma unroll 4
        for (int jj = 0; jj < 64; ++jj) {
            float ax1 = __shfl(qx1, jj, 64);
            float ay1 = __shfl(qy1, jj, 64);
            float ax2 = __shfl(qx2, jj, 64);
            float ay2 = __shfl(qy2, jj, 64);
            float aa  = __shfl(aq,  jj, 64);
            float ix1 = fmaxf(qx1, ax1), iy1 = fmaxf(qy1, ay1);
            float ix2 = fminf(qx2, ax2), iy2 = fminf(qy2, ay2);
            float inter = fmaxf(ix2 - ix1, 0.0f) * fmaxf(iy2 - iy1, 0.0f);
            float iou = inter / (aq + aa - inter);
            if (iou > NMS_THR) M |= (1ull << jj);
        }
        while (alive != 0ull && na < TOPN) {
            int j = __ffsll((unsigned long long)alive) - 1;
            if (lane == j) {
                abox[na]  = make_float4(qx1, qy1, qx2, qy2);
                aarea[na] = aq;
                float* o = out + ((size_t)b * TOPN + na) * 6;
                o[0] = fminf(fmaxf(db.x, 0.0f), 1.0f);
                o[1] = fminf(fmaxf(db.y, 0.0f), 1.0f);
                o[2] = fminf(fmaxf(db.z, 0.0f), 1.0f);
                o[3] = fminf(fmaxf(db.w, 0.0f), 1.0f);
                o[4] = __uint_as_float((uint32_t)(myk >> 32));
                o[5] = (float)c;
            }
            na++;
            aliveB = aliveB && !((M >> j) & 1ull);
            alive = __ballot(aliveB);
        }
    }
    return na;
}

// ---------------------------------------------------------------------------
// Fallback single-candidate scan step (overfull-stratum path; never taken).
// ---------------------------------------------------------------------------
__device__ __forceinline__ int scan_step_w0(
    uint64_t key, int b, const float4* __restrict__ dbox, float ofb,
    float4* abox, float* aarea, int na, float* __restrict__ out, int lane)
{
    uint32_t oid = 0xFFFFFFFFu - (uint32_t)key;
    int p = (int)(oid / NLBL);
    int c = (int)(oid - (uint32_t)p * NLBL) + 1;
    float4 db = dbox[p];
    float lo = (float)c * ofb;
    float qx1 = db.x + lo, qy1 = db.y + lo;
    float qx2 = db.z + lo, qy2 = db.w + lo;
    float aq = (qx2 - qx1) * (qy2 - qy1);
    bool sup = false;
    for (int l = lane; l < na; l += 64) {
        float4 a = abox[l];
        float ix1 = fmaxf(qx1, a.x), iy1 = fmaxf(qy1, a.y);
        float ix2 = fminf(qx2, a.z), iy2 = fminf(qy2, a.w);
        float inter = fmaxf(ix2 - ix1, 0.0f) * fmaxf(iy2 - iy1, 0.0f);
        float iou = inter / (aq + aarea[l] - inter);
        if (iou > NMS_THR) sup = true;
    }
    if (__ballot(sup) == 0ull) {
        if (lane == 0) {
            abox[na]  = make_float4(qx1, qy1, qx2, qy2);
            aarea[na] = aq;
            float* o = out + ((size_t)b * TOPN + na) * 6;
            o[0] = fminf(fmaxf(db.x, 0.0f), 1.0f);
            o[1] = fminf(fmaxf(db.y, 0.0f), 1.0f);
            o[2] = fminf(fmaxf(db.z, 0.0f), 1.0f);
            o[3] = fminf(fmaxf(db.w, 0.0f), 1.0f);
            o[4] = __uint_as_float((uint32_t)(key >> 32));
            o[5] = (float)c;
        }
        __threadfence_block();
        return na + 1;
    }
    return na;
}

// ---------------------------------------------------------------------------
// FUSED kernel: blocks [0, 752) = filter, blocks [752, 768) = nms.
// ---------------------------------------------------------------------------
__global__ __launch_bounds__(NMS_T) void fused_kernel(
    const float* __restrict__ obj,      // [B][P][NCLS]
    const float* __restrict__ deltas,   // [B][P][4]
    const float* __restrict__ priors,   // [P][4]
    int*         __restrict__ cnt,      // [B] seg-overflow ctr (memset 0)
    int*         __restrict__ hcnt,     // [B] hot-overflow ctr (memset 0)
    int*         __restrict__ doneF,    // [B][FBLK] flags (memset 0)
    uint64_t*    __restrict__ seg,      // [B][SEGS][SEGW]
    uint64_t*    __restrict__ hot,      // [B][SEGS][HOTW]
    uint64_t*    __restrict__ ovf,      // [B][OVF_CAP]
    uint64_t*    __restrict__ hovf,     // [B][OVF_CAP]
    float*       __restrict__ out)      // [B][TOPN][6]
{
    __shared__ float4   dbox[PRIORS];     // 48 KB decoded boxes (nms path)
    __shared__ int      sufx[NBINS];
    __shared__ uint64_t skey[HCAP];
    __shared__ float4   abox[112];
    __shared__ float    aarea[112];
    __shared__ uint64_t rk[NMS_T / 64];
    __shared__ float    wredF[NMS_T / 64];
    __shared__ int      wtotS[NMS_T / 64];
    __shared__ int      carryS[NMS_T / 64];
    __shared__ int cntC, loS, naS;
    __shared__ uint64_t fkS;

    const int tid  = threadIdx.x;
    const int wave = tid >> 6;
    const int lane = tid & 63;

    if (blockIdx.x < FBLK * BATCH) {
        // ==================== FILTER BLOCK ====================
        const int fb = blockIdx.x;
        const int b = fb / FBLK, blk = fb % FBLK;
        const int segId = blk * 16 + wave;
        uint64_t* myseg = seg + ((size_t)b * SEGS + segId) * SEGW;
        uint64_t* myhot = hot + ((size_t)b * SEGS + segId) * HOTW;
        const int pbase = blk * FPPB + wave * 4;

        // R10-style interleaved 4-prior softmax (bit-stable, absmax 0.0)
        float v0[4], v1[4], v2[4], v3[4];
        bool pv[4];
#pragma unroll
        for (int pp = 0; pp < 4; ++pp) {
            int p = pbase + pp;
            pv[pp] = (p < PRIORS);
            const float* x = obj + ((size_t)b * PRIORS + (pv[pp] ? p : PRIORS - 1)) * NCLS;
            v0[pp] = x[lane];
            v1[pp] = x[lane + 64];
            v2[pp] = x[lane + 128];
            v3[pp] = (lane + 192 < NCLS) ? x[lane + 192] : -FLT_MAX;
        }
        float mx[4];
#pragma unroll
        for (int pp = 0; pp < 4; ++pp)
            mx[pp] = fmaxf(fmaxf(v0[pp], v1[pp]), fmaxf(v2[pp], v3[pp]));
        for (int d = 32; d > 0; d >>= 1) {
#pragma unroll
            for (int pp = 0; pp < 4; ++pp)
                mx[pp] = fmaxf(mx[pp], __shfl_xor(mx[pp], d, 64));
        }
        float e0[4], e1[4], e2[4], e3[4], se[4];
#pragma unroll
        for (int pp = 0; pp < 4; ++pp) {
            e0[pp] = expf(v0[pp] - mx[pp]);
            e1[pp] = expf(v1[pp] - mx[pp]);
            e2[pp] = expf(v2[pp] - mx[pp]);
            e3[pp] = (lane + 192 < NCLS) ? expf(v3[pp] - mx[pp]) : 0.0f;
            se[pp] = e0[pp] + e1[pp] + e2[pp] + e3[pp];
        }
        for (int d = 32; d > 0; d >>= 1) {
#pragma unroll
            for (int pp = 0; pp < 4; ++pp)
                se[pp] += __shfl_xor(se[pp], d, 64);
        }
        int cursor = 0, hcur = 0;
#pragma unroll
        for (int pp = 0; pp < 4; ++pp) {
            float inv = 1.0f / se[pp];
            int p = pbase + pp;
            float ev[4] = { e0[pp], e1[pp], e2[pp], e3[pp] };
#pragma unroll
            for (int k = 0; k < 4; ++k) {
                int c = lane + 64 * k;
                float prob = ev[k] * inv;
                bool pass = pv[pp] && (c >= 1) && (c < NCLS) && (prob > SCORE_THR);
                uint64_t mask = __ballot(pass);
                bool hotp = pass && (prob > T0);
                uint64_t hmask = __ballot(hotp);
                if (pass) {
                    uint32_t oid = (uint32_t)(p * NLBL + (c - 1));
                    uint64_t key = ((uint64_t)__float_as_uint(prob) << 32)
                                 | (uint64_t)(0xFFFFFFFFu - oid);
                    int idx = cursor + __popcll(mask & ((1ull << lane) - 1ull));
                    if (idx < SEGW) {
                        myseg[idx] = key;
                    } else {                    // exact seg overflow (never taken)
                        int gi = atomicAdd(&cnt[b], 1);
                        if (gi < OVF_CAP) ovf[(size_t)b * OVF_CAP + gi] = key;
                    }
                    if (hotp) {
                        int hidx = hcur + __popcll(hmask & ((1ull << lane) - 1ull));
                        if (hidx < HOTW) {
                            myhot[hidx] = key;
                        } else {                // exact hot overflow (never taken)
                            int gi = atomicAdd(&hcnt[b], 1);
                            if (gi < OVF_CAP) hovf[(size_t)b * OVF_CAP + gi] = key;
                        }
                    }
                }
                cursor += (int)__popcll(mask);
                hcur   += (int)__popcll(hmask);
            }
        }
        if (lane >= (cursor < SEGW ? cursor : SEGW)) myseg[lane] = 0ull;
        if (lane < HOTW && lane >= (hcur < HOTW ? hcur : HOTW)) myhot[lane] = 0ull;

        // publish: all writes device-visible, then release the done flag
        __threadfence();
        __syncthreads();
        if (tid == 0)
            __hip_atomic_store(&doneF[b * FBLK + blk], DONE_MAGIC,
                               __ATOMIC_RELEASE, __HIP_MEMORY_SCOPE_AGENT);
        return;
    }

    // ==================== NMS BLOCK ====================
    const int b = blockIdx.x - FBLK * BATCH;
    const uint64_t* slots  = seg + (size_t)b * SLOTS;
    const uint64_t* hslots = hot + (size_t)b * SEGS * HOTW;
    const uint64_t* ovfp   = ovf  + (size_t)b * OVF_CAP;
    const uint64_t* hovfp  = hovf + (size_t)b * OVF_CAP;

    if (tid == 0) { cntC = 0; naS = 0; }
    if (tid < HCAP) skey[tid] = 0ull;

    // ---- decode 3000 priors -> LDS dbox, CONCURRENT with filter blocks ----
    float lmax = -FLT_MAX;
    for (int p = tid; p < PRIORS; p += NMS_T) {
        float4 d4 = ((const float4*)deltas)[(size_t)b * PRIORS + p];
        float4 pr = ((const float4*)priors)[p];
        float cx = d4.x * 0.1f * pr.z + pr.x;
        float cy = d4.y * 0.1f * pr.w + pr.y;
        float w  = expf(d4.z * 0.2f) * pr.z;
        float h  = expf(d4.w * 0.2f) * pr.w;
        float x1 = cx - 0.5f * w, y1 = cy - 0.5f * h;
        float x2 = cx + 0.5f * w, y2 = cy + 0.5f * h;
        dbox[p] = make_float4(x1, y1, x2, y2);
        lmax = fmaxf(lmax, fmaxf(fmaxf(x1, y1), fmaxf(x2, y2)));
    }
    for (int d = 32; d > 0; d >>= 1)
        lmax = fmaxf(lmax, __shfl_xor(lmax, d, 64));
    if (lane == 0) wredF[wave] = lmax;
    __syncthreads();
    float ofb;
    {
        float v = (lane < NMS_T / 64) ? wredF[lane] : -FLT_MAX;
        for (int d = 32; d > 0; d >>= 1) v = fmaxf(v, __shfl_xor(v, d, 64));
        ofb = v + 1.0f;                    // bitwise-identical across waves
    }

    // ---- acquire-spin on this image's 47 done flags (each wave) ----
    {
        const int* df = doneF + b * FBLK;
        for (;;) {
            int v = (lane < FBLK)
                  ? __hip_atomic_load(&df[lane], __ATOMIC_ACQUIRE,
                                      __HIP_MEMORY_SCOPE_AGENT)
                  : DONE_MAGIC;
            if (__ballot(v == DONE_MAGIC) == ~0ull) break;
            __builtin_amdgcn_s_sleep(2);
        }
    }
    int n_ovf  = cnt[b];  if (n_ovf  > OVF_CAP) n_ovf  = OVF_CAP;
    int n_hovf = hcnt[b]; if (n_hovf > OVF_CAP) n_hovf = OVF_CAP;

    // ---- FAST PATH: gather hot keys (strict desc prefix of key order) ----
    for (int j = tid; j < SEGS * HOTW; j += NMS_T) {
        uint64_t k = hslots[j];
        if (k) { int i = atomicAdd(&cntC, 1); if (i < HCAP) skey[i] = k; }
    }
    for (int j = tid; j < n_hovf; j += NMS_T) {
        uint64_t k = hovfp[j];
        if (k) { int i = atomicAdd(&cntC, 1); if (i < HCAP) skey[i] = k; }
    }
    __syncthreads();
    int hc = cntC;                          // uniform
    if (hc <= HCAP) {
        if (wave == 0) {
            uint64_t K[8];
            sort512_desc(skey, K, lane);
            int na = scan_matrix_w0(K, b, dbox, ofb, abox, aarea, 0, out, lane);
            if (lane == 0) naS = na;
        }
    }
    __syncthreads();

    // ---- EXACT FALLBACK (hot>512 or accepts<100; never with this data) ----
    if (naS < TOPN) {
        sufx[tid] = 0;
        if (tid == 0) naS = 0;              // restart: rows rewritten identically
        __syncthreads();
        for (int j = tid; j < SLOTS; j += NMS_T) {
            uint64_t k = slots[j];
            if (k) atomicAdd(&sufx[key_stratum(k)], 1);
        }
        for (int j = tid; j < n_ovf; j += NMS_T) {
            uint64_t k = ovfp[j];
            if (k) atomicAdd(&sufx[key_stratum(k)], 1);
        }
        __syncthreads();
        {
            int v = sufx[64 * wave + lane];
            int s = v;
            for (int d = 1; d < 64; d <<= 1) {
                int t = __shfl_down(s, d, 64);
                if (lane + d < 64) s += t;
            }
            if (lane == 0) wtotS[wave] = s;
            __syncthreads();
            if (wave == 0 && lane < NMS_T / 64) {
                int tv = wtotS[lane];
                int ts = tv;
                for (int d = 1; d < NMS_T / 64; d <<= 1) {
                    int t = __shfl_down(ts, d, 64);
                    if (lane + d < NMS_T / 64) ts += t;
                }
                carryS[lane] = ts - tv;
            }
            __syncthreads();
            sufx[64 * wave + lane] = s + carryS[wave];
        }
        int curHi = NBINS;
        for (;;) {
            __syncthreads();
            int naCur = naS;
            int A = (curHi < NBINS) ? sufx[curHi] : 0;
            int remaining = sufx[0] - A;
            if (naCur >= TOPN || remaining <= 0 || curHi <= 0) break;
            int target = A + HCAP;
            if (tid == 0) { loS = curHi; cntC = 0; }
            __syncthreads();
            if (tid < curHi) {
                if (sufx[tid] <= target && (tid == 0 || sufx[tid - 1] > target))
                    loS = tid;
            }
            __syncthreads();
            int lo = loS;

            if (lo < curHi) {
                for (int j = tid; j < SLOTS; j += NMS_T) {
                    uint64_t k = slots[j];
                    if (k) {
                        int s = key_stratum(k);
                        if (s >= lo && s < curHi) {
                            int i = atomicAdd(&cntC, 1);
                            if (i < HCAP) skey[i] = k;
                        }
                    }
                }
                for (int j = tid; j < n_ovf; j += NMS_T) {
                    uint64_t k = ovfp[j];
                    if (k) {
                        int s = key_stratum(k);
                        if (s >= lo && s < curHi) {
                            int i = atomicAdd(&cntC, 1);
                            if (i < HCAP) skey[i] = k;
                        }
                    }
                }
                __syncthreads();
                if (tid < HCAP && tid >= cntC) skey[tid] = 0ull;
                __syncthreads();
                if (wave == 0) {
                    uint64_t K[8];
                    sort512_desc(skey, K, lane);
                    int na = scan_matrix_w0(K, b, dbox, ofb, abox, aarea, naS, out, lane);
                    if (lane == 0) naS = na;
                }
                curHi = lo;
            } else {
                int s = curHi - 1;
                uint64_t lastK = ~0ull;
                for (;;) {
                    __syncthreads();
                    if (naS >= TOPN) break;
                    uint64_t bk = 0ull;
                    for (int j = tid; j < SLOTS; j += NMS_T) {
                        uint64_t k = slots[j];
                        if (k && key_stratum(k) == s && k < lastK && k > bk) bk = k;
                    }
                    for (int j = tid; j < n_ovf; j += NMS_T) {
                        uint64_t k = ovfp[j];
                        if (k && key_stratum(k) == s && k < lastK && k > bk) bk = k;
                    }
                    for (int d = 32; d > 0; d >>= 1) {
                        uint64_t o = __shfl_xor((unsigned long long)bk, d, 64);
                        bk = (o > bk) ? o : bk;
                    }
                    if (lane == 0) rk[wave] = bk;
                    __syncthreads();
                    if (tid == 0) {
                        uint64_t fk = rk[0];
                        for (int w = 1; w < NMS_T / 64; ++w) fk = (rk[w] > fk) ? rk[w] : fk;
                        fkS = fk;
                    }
                    __syncthreads();
                    uint64_t fk = fkS;
                    if (fk == 0ull) break;
                    if (wave == 0) {
                        int nal = naS;
                        nal = scan_step_w0(fk, b, dbox, ofb, abox, aarea, nal, out, lane);
                        if (lane == 0) naS = nal;
                    }
                    lastK = fk;
                }
                curHi = s;
            }
        }
        __syncthreads();
    }
    // ---- zero-fill rows naS..99 (harness poisons d_out) ----
    int naF = naS;
    for (int idx = tid; idx < (TOPN - naF) * 6; idx += NMS_T)
        out[(size_t)b * TOPN * 6 + (size_t)naF * 6 + idx] = 0.0f;
}

// ---------------------------------------------------------------------------
extern "C" void kernel_launch(void* const* d_in, const int* in_sizes, int n_in,
                              void* d_out, int out_size, void* d_ws, size_t ws_size,
                              hipStream_t stream)
{
    const float* deltas = (const float*)d_in[0];
    const float* obj    = (const float*)d_in[1];
    const float* priors = (const float*)d_in[2];
    float* out = (float*)d_out;

    char* ws = (char*)d_ws;
    int*      cnt   = (int*)ws;                             // 64 B
    int*      hcnt  = (int*)(ws + 64);                      // 64 B
    int*      doneF = (int*)(ws + 128);                     // B*FBLK*4 = 3008 B
    size_t    zBytes = 128 + (size_t)BATCH * FBLK * 4;      // 3136
    size_t    off    = (zBytes + 255) & ~(size_t)255;       // 3328
    uint64_t* hotA = (uint64_t*)(ws + off);                 // B*SEGS*HOTW*8 = 770 KB
    uint64_t* segA = hotA + (size_t)BATCH * SEGS * HOTW;    // B*SLOTS*8 = 6.2 MB
    uint64_t* ovfA = segA + (size_t)BATCH * SLOTS;          // 128 KB
    uint64_t* hovA = ovfA + (size_t)BATCH * OVF_CAP;        // 128 KB

    hipMemsetAsync(ws, 0, zBytes, stream);
    fused_kernel<<<FBLK * BATCH + BATCH, NMS_T, 0, stream>>>(
        obj, deltas, priors, cnt, hcnt, doneF, segA, hotA, ovfA, hovA, out);
}